// Round 14
// baseline (271.149 us; speedup 1.0000x reference)
//
#include <hip/hip_runtime.h>
#include <stdint.h>

#define DSR   0.90483741803595952f   // exp(-1/10)
#define DREF  0.36787944117144233f   // exp(-1)
#define THETA 10.0f
#define REFAMP 20.0f                 // SCALE_REF * THETA

#define NB 16
#define TT 500
#define TP 512
#define F1 6300
#define KP 6400      // K padded (multiple of 128)
#define NKS 50       // KP/128
#define O1 1024
#define NC 8192      // NB * TP columns
#define FT 156
#define OT 50
#define O2 10
#define OF 20

typedef __attribute__((ext_vector_type(4)))  float f32x4;
typedef __attribute__((ext_vector_type(4)))  int   i32x4;
typedef __attribute__((ext_vector_type(16))) int   i32x16;

#define GLL16(g, l) __builtin_amdgcn_global_load_lds( \
    (const __attribute__((address_space(1))) void*)(g), \
    (__attribute__((address_space(3))) void*)(l), 16, 0, 0)

// ============ K0: fused prep (bitmap | weight planes) =======================
__global__ void __launch_bounds__(512) k_prep(const float* __restrict__ xv,
                                              const float* __restrict__ W,
                                              unsigned char* __restrict__ Bg,
                                              char* __restrict__ H0,
                                              char* __restrict__ H1) {
  __shared__ unsigned char tb[64][516];   // 33 KB, rows 129 dwords (odd) -> 2-way
  int bx = blockIdx.x, tid = threadIdx.x;
  if (bx < 1600) {
    int ft = bx % 100, n = bx / 100;
    int f0 = ft * 64;
    int ks = ft >> 1, half = ft & 1;
#pragma unroll
    for (int it = 0; it < 16; ++it) {
      int idx = it * 512 + tid;
      int row = idx >> 7, c4 = idx & 127;
      int f = f0 + row, t = c4 * 4;
      uchar4 b = make_uchar4(0, 0, 0, 0);
      if (f < F1) {
        if (t + 3 < TT) {
          f32x4 v = *(const f32x4*)(xv + ((size_t)n * F1 + f) * TT + t);
          b.x = (v[0] != 0.f); b.y = (v[1] != 0.f);
          b.z = (v[2] != 0.f); b.w = (v[3] != 0.f);
        } else {
#pragma unroll
          for (int j = 0; j < 4; ++j)
            if (t + j < TT) {
              float v = xv[((size_t)n * F1 + f) * TT + t + j];
              ((unsigned char*)&b)[j] = (v != 0.f);
            }
        }
      }
      *(uchar4*)&tb[row][t] = b;
    }
    __syncthreads();
    int lane = tid & 63, w = tid >> 6;    // 8 waves, 64 t-cols each
#pragma unroll 8
    for (int i = 0; i < 64; ++i) {
      int tl = w * 64 + i;
      unsigned long long mask = __ballot(tb[lane][tl] != 0);
      if (lane == 0) {
        unsigned lo = (unsigned)mask, hi = (unsigned)(mask >> 32);
        unsigned w0 = __builtin_amdgcn_perm(hi, lo, 0x05040100u);
        unsigned w1 = __builtin_amdgcn_perm(hi, lo, 0x07060302u);
        int col = n * TP + tl;
        unsigned char* g = Bg + ((size_t)ks * 8192 + col) * 16 + half * 4;
        *(unsigned*)(g) = w0;
        *(unsigned*)(g + 8) = w1;
      }
    }
  } else {
    int sb = bx - 1600;           // 0..255, 4 o-rows each
    int o0 = sb * 4;
#pragma unroll
    for (int it = 0; it < 13; ++it) {
      int e = it * 2048 + tid * 4;
      if (e < 25600) {
        int row = e / 6400;
        int f = e - row * 6400;
        int o = o0 + row;
        float w4[4] = {0.f, 0.f, 0.f, 0.f};
        if (f < F1) {
          const f32x4 v = *(const f32x4*)(W + (size_t)o * F1 + f);
          w4[0] = v[0]; w4[1] = v[1]; w4[2] = v[2]; w4[3] = v[3];
        }
        char c0[4], c1[4];
#pragma unroll
        for (int j = 0; j < 4; ++j) {
          int wq = __float2int_rn(w4[j] * 32768.0f);
          int h0 = ((wq + 128) & 255) - 128;
          int h1 = (wq - h0) >> 8;
          c0[j] = (char)h0; c1[j] = (char)h1;
        }
        *(char4*)(H0 + (size_t)o * KP + f) = make_char4(c0[0], c0[1], c0[2], c0[3]);
        *(char4*)(H1 + (size_t)o * KP + f) = make_char4(c1[0], c1[1], c1[2], c1[3]);
      }
    }
  }
}

// ============ K2: GEMM C = W * bits^T, 2-plane base-256, B in registers =====
// BODY v2: B-expand for kk=0,1 hoisted BEFORE the vmcnt/barrier (compiler
// inserts a counted wait for just the bregs loads; A-stage stays in flight),
// LDB issued before STAGE so B lands first. kk=2,3 expand inline under MFMAs.
__global__ void __launch_bounds__(512, 4) k_gemm(const char* __restrict__ H0,
                                                 const char* __restrict__ H1,
                                                 const unsigned char* __restrict__ Bg,
                                                 float* __restrict__ C) {
  __shared__ char A0[2][128 * 128];
  __shared__ char A1[2][128 * 128];
  int tid = threadIdx.x, bid = blockIdx.x;
  int gy = bid & 7, gx = bid >> 3;          // 8 gy (XCD-pinned) x 64 gx
  int wave = tid >> 6, lane = tid & 63;
  int wr = wave >> 1, wc = wave & 1;        // 4 x 2, wave tile 32x64
  int l31 = lane & 31, h = lane >> 5;

  i32x16 acc0[2], acc1[2];
#pragma unroll
  for (int nn = 0; nn < 2; ++nn) { acc0[nn] = (i32x16)0; acc1[nn] = (i32x16)0; }

  size_t ga[2]; unsigned ldsa[2];
#pragma unroll
  for (int j = 0; j < 2; ++j) {
    int p = j * 512 + tid;
    int row = p >> 3;
    int src = (p & 7) ^ (row & 7);
    ga[j] = (size_t)(gy * 128 + row) * KP + src * 16;
    ldsa[j] = (unsigned)p * 16u;
  }
  const unsigned char* bp[2];
#pragma unroll
  for (int nn = 0; nn < 2; ++nn)
    bp[nn] = Bg + ((size_t)(gx * 128 + wc * 64 + nn * 32 + l31) * 16) + h * 8;

  int ra = wr * 32 + l31;
  int offA[4];
#pragma unroll
  for (int kk = 0; kk < 4; ++kk)
    offA[kk] = ra * 128 + (((kk * 2 + h) ^ (ra & 7)) * 16);

#define STAGE(ks, buf) do {                                       \
    size_t ko = (size_t)(ks) * 128;                               \
    GLL16(H0 + ga[0] + ko, (char*)&A0[buf][0] + ldsa[0]);         \
    GLL16(H0 + ga[1] + ko, (char*)&A0[buf][0] + ldsa[1]);         \
    GLL16(H1 + ga[0] + ko, (char*)&A1[buf][0] + ldsa[0]);         \
    GLL16(H1 + ga[1] + ko, (char*)&A1[buf][0] + ldsa[1]);         \
  } while (0)

#define LDB(ks, arr) do {                                         \
    _Pragma("unroll")                                             \
    for (int nn = 0; nn < 2; ++nn)                                \
      arr[nn] = *(const uint2*)(bp[nn] + (size_t)(ks) * 131072);  \
  } while (0)

#define EXPAND16(xx, dst) do {                                    \
    _Pragma("unroll")                                             \
    for (int w = 0; w < 4; ++w) {                                 \
      unsigned nib = ((xx) >> (4 * w)) & 0xFu;                    \
      dst[w] = (int)((nib * 0x00204081u) & 0x01010101u);          \
    }                                                             \
  } while (0)

#define BODY(ks, buf, bregs) do {                                               \
    i32x4 bv0[2], bv1[2];                                                       \
    _Pragma("unroll")                                                           \
    for (int nn = 0; nn < 2; ++nn) {                                            \
      unsigned xx = bregs[nn].x;                                                \
      unsigned xlo = xx & 0xFFFFu, xhi = xx >> 16;                              \
      EXPAND16(xlo, bv0[nn]);                                                   \
      EXPAND16(xhi, bv1[nn]);                                                   \
    }                                                                           \
    if ((ks) == NKS - 1) { asm volatile("s_waitcnt vmcnt(0)" ::: "memory"); }   \
    else                 { asm volatile("s_waitcnt vmcnt(6)" ::: "memory"); }   \
    __builtin_amdgcn_sched_barrier(0);                                          \
    __builtin_amdgcn_s_barrier();                                               \
    __builtin_amdgcn_sched_barrier(0);                                          \
    {                                                                           \
      i32x4 fa0 = *(const i32x4*)(&A0[buf][0] + offA[0]);                       \
      i32x4 fa1 = *(const i32x4*)(&A1[buf][0] + offA[0]);                       \
      __builtin_amdgcn_s_setprio(1);                                            \
      acc0[0] = __builtin_amdgcn_mfma_i32_32x32x32_i8(fa0, bv0[0], acc0[0], 0, 0, 0); \
      acc1[0] = __builtin_amdgcn_mfma_i32_32x32x32_i8(fa1, bv0[0], acc1[0], 0, 0, 0); \
      acc0[1] = __builtin_amdgcn_mfma_i32_32x32x32_i8(fa0, bv0[1], acc0[1], 0, 0, 0); \
      acc1[1] = __builtin_amdgcn_mfma_i32_32x32x32_i8(fa1, bv0[1], acc1[1], 0, 0, 0); \
      __builtin_amdgcn_s_setprio(0);                                            \
    }                                                                           \
    {                                                                           \
      i32x4 fa0 = *(const i32x4*)(&A0[buf][0] + offA[1]);                       \
      i32x4 fa1 = *(const i32x4*)(&A1[buf][0] + offA[1]);                       \
      __builtin_amdgcn_s_setprio(1);                                            \
      acc0[0] = __builtin_amdgcn_mfma_i32_32x32x32_i8(fa0, bv1[0], acc0[0], 0, 0, 0); \
      acc1[0] = __builtin_amdgcn_mfma_i32_32x32x32_i8(fa1, bv1[0], acc1[0], 0, 0, 0); \
      acc0[1] = __builtin_amdgcn_mfma_i32_32x32x32_i8(fa0, bv1[1], acc0[1], 0, 0, 0); \
      acc1[1] = __builtin_amdgcn_mfma_i32_32x32x32_i8(fa1, bv1[1], acc1[1], 0, 0, 0); \
      __builtin_amdgcn_s_setprio(0);                                            \
    }                                                                           \
    _Pragma("unroll")                                                           \
    for (int kk = 2; kk < 4; ++kk) {                                            \
      i32x4 bv[2];                                                              \
      _Pragma("unroll")                                                         \
      for (int nn = 0; nn < 2; ++nn) {                                          \
        unsigned xx = bregs[nn].y >> ((kk & 1) * 16);                           \
        xx &= 0xFFFFu;                                                          \
        EXPAND16(xx, bv[nn]);                                                   \
      }                                                                         \
      i32x4 fa0 = *(const i32x4*)(&A0[buf][0] + offA[kk]);                      \
      i32x4 fa1 = *(const i32x4*)(&A1[buf][0] + offA[kk]);                      \
      __builtin_amdgcn_s_setprio(1);                                            \
      acc0[0] = __builtin_amdgcn_mfma_i32_32x32x32_i8(fa0, bv[0], acc0[0], 0, 0, 0); \
      acc1[0] = __builtin_amdgcn_mfma_i32_32x32x32_i8(fa1, bv[0], acc1[0], 0, 0, 0); \
      acc0[1] = __builtin_amdgcn_mfma_i32_32x32x32_i8(fa0, bv[1], acc0[1], 0, 0, 0); \
      acc1[1] = __builtin_amdgcn_mfma_i32_32x32x32_i8(fa1, bv[1], acc1[1], 0, 0, 0); \
      __builtin_amdgcn_s_setprio(0);                                            \
    }                                                                           \
    __builtin_amdgcn_s_barrier();                                               \
    __builtin_amdgcn_sched_barrier(0);                                          \
    if ((ks) + 2 < NKS) { LDB((ks) + 2, bregs); STAGE((ks) + 2, buf); }         \
  } while (0)

  uint2 bA[2], bB[2];
  LDB(0, bA); STAGE(0, 0);
  LDB(1, bB); STAGE(1, 1);

  for (int ks = 0; ks < NKS; ks += 2) {
    BODY(ks, 0, bA);
    BODY(ks + 1, 1, bB);
  }
#undef BODY
#undef EXPAND16
#undef LDB
#undef STAGE

#pragma unroll
  for (int nn = 0; nn < 2; ++nn) {
    int ob = gy * 128 + wr * 32;
    int cb = gx * 128 + wc * 64 + nn * 32 + l31;
#pragma unroll
    for (int reg = 0; reg < 16; ++reg) {
      int row = (reg & 3) + 8 * (reg >> 2) + 4 * h;
      int v = acc0[nn][reg] + (acc1[nn][reg] << 8);
      C[(size_t)(ob + row) * NC + cb] = (float)v * (1.0f / 32768.0f);
    }
  }
}

// ============ K3: fused {psp+spike+Wv2-partial | tactile} ===================
__global__ void __launch_bounds__(256) k_spk1(const float* __restrict__ C,
                                              const float* __restrict__ Wv2,
                                              float* __restrict__ a2part,
                                              const float* __restrict__ xt,
                                              const float* __restrict__ Wt,
                                              unsigned char* __restrict__ s_tact) {
  __shared__ char smem[38400];   // union: spkb 512*68 + w2s | tact atv 512*14*4
  int bx = blockIdx.x, tid = threadIdx.x;
  if (bx < 256) {
    unsigned char* spkb = (unsigned char*)smem;          // [t][ch] stride 68
    float* w2s = (float*)(smem + 34816);                 // [10][64]
    int og = bx >> 4, n = bx & 15;
    for (int i = tid; i < O2 * 64; i += 256)
      w2s[i] = Wv2[(i >> 6) * O1 + og * 64 + (i & 63)];
    if (tid < 64) {
      const float* crow = C + (size_t)(og * 64 + tid) * NC + n * TP;
      float p = 0.f, r = 0.f;
      f32x4 va = *(const f32x4*)(crow);
      f32x4 vb = *(const f32x4*)(crow + 4);
      for (int i = 0; i < TP; i += 8) {
        f32x4 na, nb;
        if (i + 8 < TP) {
          na = *(const f32x4*)(crow + i + 8);
          nb = *(const f32x4*)(crow + i + 12);
        }
        float u[8];
#pragma unroll
        for (int j = 0; j < 4; ++j) { u[j] = va[j]; u[4 + j] = vb[j]; }
#pragma unroll
        for (int j = 0; j < 8; ++j) {
          p = DSR * p + u[j];
          float v = p + r;
          bool s = (v >= THETA);
          r = DREF * (r - (s ? REFAMP : 0.f));
          spkb[(i + j) * 68 + tid] = s ? (unsigned char)1 : (unsigned char)0;
        }
        va = na; vb = nb;
      }
    }
    __syncthreads();
    if (tid < 128) {
#pragma unroll
      for (int k = 0; k < 4; ++k) {
        int t = tid + k * 128;
        float acc[O2];
#pragma unroll
        for (int o = 0; o < O2; ++o) acc[o] = 0.f;
        for (int row = 0; row < 64; ++row) {
          float s = (spkb[t * 68 + row] != 0) ? 1.f : 0.f;
#pragma unroll
          for (int o = 0; o < O2; ++o) acc[o] = fmaf(w2s[o * 64 + row], s, acc[o]);
        }
#pragma unroll
        for (int o = 0; o < O2; ++o)
          a2part[(((size_t)og * NB + n) * O2 + o) * TP + t] = acc[o];
      }
    }
  } else {
    float* atv = (float*)smem;    // [t][14]
    int blk = bx - 256;
    int n = blk >> 2, g = blk & 3;
    int o0 = g * 13;
    int cnt = (o0 + 13 <= OT) ? 13 : (OT - o0);   // 13,13,13,11
    int t0 = tid, t1 = tid + 256;
    {
      float acc0[13], acc1[13];
#pragma unroll
      for (int o = 0; o < 13; ++o) { acc0[o] = 0.f; acc1[o] = 0.f; }
      for (int f = 0; f < FT; ++f) {
        float x0 = (t0 < TT) ? xt[((size_t)n * FT + f) * TT + t0] : 0.f;
        float x1 = (t1 < TT) ? xt[((size_t)n * FT + f) * TT + t1] : 0.f;
#pragma unroll
        for (int o = 0; o < 13; ++o) {
          float w = (o < cnt) ? Wt[(o0 + o) * FT + f] : 0.f;
          acc0[o] = fmaf(w, x0, acc0[o]);
          acc1[o] = fmaf(w, x1, acc1[o]);
        }
      }
#pragma unroll
      for (int o = 0; o < 13; ++o) {
        atv[t0 * 14 + o] = acc0[o];
        atv[t1 * 14 + o] = acc1[o];
      }
    }
    __syncthreads();
    if (tid < cnt) {
      float p = 0.f, r = 0.f;
      unsigned char* op = s_tact + ((size_t)n * OT + o0 + tid) * TT;
      for (int i = 0; i < TT; i += 10) {
        float u[10];
#pragma unroll
        for (int j = 0; j < 10; ++j) u[j] = atv[(i + j) * 14 + tid];
#pragma unroll
        for (int j = 0; j < 10; ++j) {
          p = DSR * p + u[j];
          float v = p + r;
          bool s = (v >= THETA);
          r = DREF * (r - (s ? REFAMP : 0.f));
          op[i + j] = s ? (unsigned char)1 : (unsigned char)0;
        }
      }
    }
  }
}

// ============ K3b: og-reduce + vis psp scan -> u2s spike bytes ==============
__global__ void __launch_bounds__(256) k_vis(const float* __restrict__ a2part,
                                             unsigned char* __restrict__ u2s) {
  __shared__ float su[TP];
  int bx = blockIdx.x, tid = threadIdx.x;
  int n = bx / O2, o = bx - n * O2;
  float s0 = 0.f, s1 = 0.f;
#pragma unroll
  for (int og = 0; og < NB; ++og) {
    const float* row = a2part + (((size_t)og * NB + n) * O2 + o) * TP;
    s0 += row[tid];
    s1 += row[tid + 256];
  }
  su[tid] = s0;
  su[tid + 256] = s1;
  __syncthreads();
  if (tid == 0) {
    float p = 0.f, r = 0.f;
    unsigned char* op = u2s + ((size_t)n * O2 + o) * TP;
    for (int i = 0; i < TT; i += 10) {
      float u[10];
#pragma unroll
      for (int j = 0; j < 10; ++j) u[j] = su[i + j];
#pragma unroll
      for (int j = 0; j < 10; ++j) {
        p = DSR * p + u[j];
        float v = p + r;
        bool s = (v >= THETA);
        r = DREF * (r - (s ? REFAMP : 0.f));
        op[i + j] = s ? (unsigned char)1 : (unsigned char)0;
      }
    }
  }
}

// ============ K4: Wf @ [s_tact; s_vis] -> psp+spike -> out ==================
__global__ void __launch_bounds__(512) k_finish(const unsigned char* __restrict__ u2s,
                                                const unsigned char* __restrict__ s_tact,
                                                const float* __restrict__ Wf,
                                                float* __restrict__ out) {
  __shared__ float af[TP * 21];
  int n = blockIdx.x, t = threadIdx.x;
  if (t < TT) {
    float acc[OF];
#pragma unroll
    for (int o = 0; o < OF; ++o) acc[o] = 0.f;
    for (int f = 0; f < OT; ++f) {
      float s = (float)s_tact[((size_t)n * OT + f) * TT + t];
#pragma unroll
      for (int o = 0; o < OF; ++o) acc[o] = fmaf(Wf[o * 60 + f], s, acc[o]);
    }
#pragma unroll
    for (int f = 0; f < O2; ++f) {
      float s = (float)u2s[((size_t)n * O2 + f) * TP + t];
#pragma unroll
      for (int o = 0; o < OF; ++o) acc[o] = fmaf(Wf[o * 60 + OT + f], s, acc[o]);
    }
#pragma unroll
    for (int o = 0; o < OF; ++o) af[t * 21 + o] = acc[o];
  }
  __syncthreads();
  if (t < OF) {
    float p = 0.f, r = 0.f;
    float* op = out + ((size_t)n * OF + t) * TT;
    for (int i = 0; i < TT; i += 10) {
      float u[10];
#pragma unroll
      for (int j = 0; j < 10; ++j) u[j] = af[(i + j) * 21 + t];
#pragma unroll
      for (int j = 0; j < 10; ++j) {
        p = DSR * p + u[j];
        float v = p + r;
        bool s = (v >= THETA);
        r = DREF * (r - (s ? REFAMP : 0.f));
        op[i + j] = s ? 1.f : 0.f;
      }
    }
  }
}

extern "C" void kernel_launch(void* const* d_in, const int* in_sizes, int n_in,
                              void* d_out, int out_size, void* d_ws, size_t ws_size,
                              hipStream_t stream) {
  (void)in_sizes; (void)n_in; (void)out_size; (void)ws_size;
  const float* xt  = (const float*)d_in[0];
  const float* xv  = (const float*)d_in[1];
  const float* Wt  = (const float*)d_in[2];
  const float* Wv1 = (const float*)d_in[3];
  const float* Wv2 = (const float*)d_in[4];
  const float* Wf  = (const float*)d_in[5];
  float* out = (float*)d_out;

  char* ws = (char*)d_ws;
  size_t off = 0;
  auto carve = [&](size_t bytes) {
    char* p = ws + off;
    off += (bytes + 255) & ~(size_t)255;
    return p;
  };
  char*          H0    = carve((size_t)O1 * KP);
  char*          H1    = carve((size_t)O1 * KP);
  unsigned char* Bg    = (unsigned char*)carve((size_t)NKS * 8192 * 16);
  float*         a1    = (float*)carve((size_t)O1 * NC * 4);
  unsigned char* stact = (unsigned char*)carve((size_t)NB * OT * TT);
  float*         a2p   = (float*)carve((size_t)NB * NB * O2 * TP * 4);
  unsigned char* u2s   = (unsigned char*)carve((size_t)NB * O2 * TP);

  k_prep<<<dim3(1856), dim3(512), 0, stream>>>(xv, Wv1, Bg, H0, H1);
  k_gemm<<<dim3(512), dim3(512), 0, stream>>>(H0, H1, Bg, a1);
  k_spk1<<<dim3(320), dim3(256), 0, stream>>>(a1, Wv2, a2p, xt, Wt, stact);
  k_vis<<<dim3(160), dim3(256), 0, stream>>>(a2p, u2s);
  k_finish<<<dim3(NB), dim3(512), 0, stream>>>(u2s, stact, Wf, out);
}

// Round 15
// 260.529 us; speedup vs baseline: 1.0408x; 1.0408x over previous
//
#include <hip/hip_runtime.h>
#include <stdint.h>

#define DSR   0.90483741803595952f   // exp(-1/10)
#define DREF  0.36787944117144233f   // exp(-1)
#define THETA 10.0f
#define REFAMP 20.0f                 // SCALE_REF * THETA

#define NB 16
#define TT 500
#define TP 512
#define F1 6300
#define KP 6400      // K padded (multiple of 128)
#define NKS 50       // KP/128 (even)
#define O1 1024
#define NC 8192      // NB * TP columns
#define FT 156
#define OT 50
#define O2 10
#define OF 20

typedef __attribute__((ext_vector_type(4)))  float f32x4;
typedef __attribute__((ext_vector_type(4)))  int   i32x4;
typedef __attribute__((ext_vector_type(16))) int   i32x16;

#define GLL16(g, l) __builtin_amdgcn_global_load_lds( \
    (const __attribute__((address_space(1))) void*)(g), \
    (__attribute__((address_space(3))) void*)(l), 16, 0, 0)

// ============ K0: fused prep (bitmap | weight planes) =======================
__global__ void __launch_bounds__(512) k_prep(const float* __restrict__ xv,
                                              const float* __restrict__ W,
                                              unsigned char* __restrict__ Bg,
                                              char* __restrict__ H0,
                                              char* __restrict__ H1) {
  __shared__ unsigned char tb[64][516];   // 33 KB, rows 129 dwords (odd) -> 2-way
  int bx = blockIdx.x, tid = threadIdx.x;
  if (bx < 1600) {
    int ft = bx % 100, n = bx / 100;
    int f0 = ft * 64;
    int ks = ft >> 1, half = ft & 1;
#pragma unroll
    for (int it = 0; it < 16; ++it) {
      int idx = it * 512 + tid;
      int row = idx >> 7, c4 = idx & 127;
      int f = f0 + row, t = c4 * 4;
      uchar4 b = make_uchar4(0, 0, 0, 0);
      if (f < F1) {
        if (t + 3 < TT) {
          f32x4 v = *(const f32x4*)(xv + ((size_t)n * F1 + f) * TT + t);
          b.x = (v[0] != 0.f); b.y = (v[1] != 0.f);
          b.z = (v[2] != 0.f); b.w = (v[3] != 0.f);
        } else {
#pragma unroll
          for (int j = 0; j < 4; ++j)
            if (t + j < TT) {
              float v = xv[((size_t)n * F1 + f) * TT + t + j];
              ((unsigned char*)&b)[j] = (v != 0.f);
            }
        }
      }
      *(uchar4*)&tb[row][t] = b;
    }
    __syncthreads();
    int lane = tid & 63, w = tid >> 6;    // 8 waves, 64 t-cols each
#pragma unroll 8
    for (int i = 0; i < 64; ++i) {
      int tl = w * 64 + i;
      unsigned long long mask = __ballot(tb[lane][tl] != 0);
      if (lane == 0) {
        unsigned lo = (unsigned)mask, hi = (unsigned)(mask >> 32);
        unsigned w0 = __builtin_amdgcn_perm(hi, lo, 0x05040100u);
        unsigned w1 = __builtin_amdgcn_perm(hi, lo, 0x07060302u);
        int col = n * TP + tl;
        unsigned char* g = Bg + ((size_t)ks * 8192 + col) * 16 + half * 4;
        *(unsigned*)(g) = w0;
        *(unsigned*)(g + 8) = w1;
      }
    }
  } else {
    int sb = bx - 1600;           // 0..255, 4 o-rows each
    int o0 = sb * 4;
#pragma unroll
    for (int it = 0; it < 13; ++it) {
      int e = it * 2048 + tid * 4;
      if (e < 25600) {
        int row = e / 6400;
        int f = e - row * 6400;
        int o = o0 + row;
        float w4[4] = {0.f, 0.f, 0.f, 0.f};
        if (f < F1) {
          const f32x4 v = *(const f32x4*)(W + (size_t)o * F1 + f);
          w4[0] = v[0]; w4[1] = v[1]; w4[2] = v[2]; w4[3] = v[3];
        }
        char c0[4], c1[4];
#pragma unroll
        for (int j = 0; j < 4; ++j) {
          int wq = __float2int_rn(w4[j] * 32768.0f);
          int h0 = ((wq + 128) & 255) - 128;
          int h1 = (wq - h0) >> 8;
          c0[j] = (char)h0; c1[j] = (char)h1;
        }
        *(char4*)(H0 + (size_t)o * KP + f) = make_char4(c0[0], c0[1], c0[2], c0[3]);
        *(char4*)(H1 + (size_t)o * KP + f) = make_char4(c1[0], c1[1], c1[2], c1[3]);
      }
    }
  }
}

// ============ K2: GEMM C = W * bits^T, 2-plane base-256, B in registers =====
// Single-barrier 2-phase schedule (guide T3 minimum recipe): per K-step,
// {issue STAGE(ks+1 -> buf^1) + LDB(ks+1)} -> MFMA on buf[cur] -> vmcnt(0)
// -> s_barrier. End-of-iter barrier makes next iter's buffer overwrite safe.
__global__ void __launch_bounds__(512, 4) k_gemm(const char* __restrict__ H0,
                                                 const char* __restrict__ H1,
                                                 const unsigned char* __restrict__ Bg,
                                                 float* __restrict__ C) {
  __shared__ char A0[2][128 * 128];
  __shared__ char A1[2][128 * 128];
  int tid = threadIdx.x, bid = blockIdx.x;
  int gy = bid & 7, gx = bid >> 3;          // 8 gy (XCD-pinned) x 64 gx
  int wave = tid >> 6, lane = tid & 63;
  int wr = wave >> 1, wc = wave & 1;        // 4 x 2, wave tile 32x64
  int l31 = lane & 31, h = lane >> 5;

  i32x16 acc0[2], acc1[2];
#pragma unroll
  for (int nn = 0; nn < 2; ++nn) { acc0[nn] = (i32x16)0; acc1[nn] = (i32x16)0; }

  size_t ga[2]; unsigned ldsa[2];
#pragma unroll
  for (int j = 0; j < 2; ++j) {
    int p = j * 512 + tid;
    int row = p >> 3;
    int src = (p & 7) ^ (row & 7);
    ga[j] = (size_t)(gy * 128 + row) * KP + src * 16;
    ldsa[j] = (unsigned)p * 16u;
  }
  const unsigned char* bp[2];
#pragma unroll
  for (int nn = 0; nn < 2; ++nn)
    bp[nn] = Bg + ((size_t)(gx * 128 + wc * 64 + nn * 32 + l31) * 16) + h * 8;

  int ra = wr * 32 + l31;
  int offA[4];
#pragma unroll
  for (int kk = 0; kk < 4; ++kk)
    offA[kk] = ra * 128 + (((kk * 2 + h) ^ (ra & 7)) * 16);

#define STAGE(ks, buf) do {                                       \
    size_t ko = (size_t)(ks) * 128;                               \
    GLL16(H0 + ga[0] + ko, (char*)&A0[buf][0] + ldsa[0]);         \
    GLL16(H0 + ga[1] + ko, (char*)&A0[buf][0] + ldsa[1]);         \
    GLL16(H1 + ga[0] + ko, (char*)&A1[buf][0] + ldsa[0]);         \
    GLL16(H1 + ga[1] + ko, (char*)&A1[buf][0] + ldsa[1]);         \
  } while (0)

#define LDB(ks, arr) do {                                         \
    _Pragma("unroll")                                             \
    for (int nn = 0; nn < 2; ++nn)                                \
      arr[nn] = *(const uint2*)(bp[nn] + (size_t)(ks) * 131072);  \
  } while (0)

#define MFMASEC(buf, bregs) do {                                                \
    _Pragma("unroll")                                                           \
    for (int kk = 0; kk < 4; ++kk) {                                            \
      i32x4 fa0 = *(const i32x4*)(&A0[buf][0] + offA[kk]);                      \
      i32x4 fa1 = *(const i32x4*)(&A1[buf][0] + offA[kk]);                      \
      i32x4 bv[2];                                                              \
      _Pragma("unroll")                                                         \
      for (int nn = 0; nn < 2; ++nn) {                                          \
        unsigned x = ((kk < 2) ? bregs[nn].x : bregs[nn].y) >> ((kk & 1) * 16); \
        x &= 0xFFFFu;                                                           \
        _Pragma("unroll")                                                       \
        for (int w = 0; w < 4; ++w) {                                           \
          unsigned nib = (x >> (4 * w)) & 0xFu;                                 \
          bv[nn][w] = (int)((nib * 0x00204081u) & 0x01010101u);                 \
        }                                                                       \
      }                                                                         \
      __builtin_amdgcn_s_setprio(1);                                            \
      _Pragma("unroll")                                                         \
      for (int nn = 0; nn < 2; ++nn) {                                          \
        acc0[nn] = __builtin_amdgcn_mfma_i32_32x32x32_i8(fa0, bv[nn], acc0[nn], 0, 0, 0); \
        acc1[nn] = __builtin_amdgcn_mfma_i32_32x32x32_i8(fa1, bv[nn], acc1[nn], 0, 0, 0); \
      }                                                                         \
      __builtin_amdgcn_s_setprio(0);                                            \
    }                                                                           \
  } while (0)

#define ENDBAR() do {                                             \
    asm volatile("s_waitcnt vmcnt(0)" ::: "memory");              \
    __builtin_amdgcn_sched_barrier(0);                            \
    __builtin_amdgcn_s_barrier();                                 \
    __builtin_amdgcn_sched_barrier(0);                            \
  } while (0)

  uint2 bA[2], bB[2];
  LDB(0, bA);
  STAGE(0, 0);
  ENDBAR();                       // stage(0) landed in buf0, all waves synced

  for (int ks = 0; ks < NKS; ks += 2) {
    // even iter: compute buf0/bA, stage ks+1 -> buf1
    if (ks + 1 < NKS) { LDB(ks + 1, bB); STAGE(ks + 1, 1); }
    MFMASEC(0, bA);
    ENDBAR();
    // odd iter: compute buf1/bB, stage ks+2 -> buf0
    if (ks + 2 < NKS) { LDB(ks + 2, bA); STAGE(ks + 2, 0); }
    MFMASEC(1, bB);
    ENDBAR();
  }
#undef ENDBAR
#undef MFMASEC
#undef LDB
#undef STAGE

  // C/D 32x32: col = lane&31, row = (reg&3) + 8*(reg>>2) + 4*h
#pragma unroll
  for (int nn = 0; nn < 2; ++nn) {
    int ob = gy * 128 + wr * 32;
    int cb = gx * 128 + wc * 64 + nn * 32 + l31;
#pragma unroll
    for (int reg = 0; reg < 16; ++reg) {
      int row = (reg & 3) + 8 * (reg >> 2) + 4 * h;
      int v = acc0[nn][reg] + (acc1[nn][reg] << 8);
      C[(size_t)(ob + row) * NC + cb] = (float)v * (1.0f / 32768.0f);
    }
  }
}

// ============ K3: fused {psp+spike+Wv2-partial | tactile} ===================
__global__ void __launch_bounds__(256) k_spk1(const float* __restrict__ C,
                                              const float* __restrict__ Wv2,
                                              float* __restrict__ a2part,
                                              const float* __restrict__ xt,
                                              const float* __restrict__ Wt,
                                              unsigned char* __restrict__ s_tact) {
  __shared__ char smem[38400];   // union: spkb 512*68 + w2s | tact atv 512*14*4
  int bx = blockIdx.x, tid = threadIdx.x;
  if (bx < 256) {
    unsigned char* spkb = (unsigned char*)smem;          // [t][ch] stride 68
    float* w2s = (float*)(smem + 34816);                 // [10][64]
    int og = bx >> 4, n = bx & 15;
    for (int i = tid; i < O2 * 64; i += 256)
      w2s[i] = Wv2[(i >> 6) * O1 + og * 64 + (i & 63)];
    if (tid < 64) {
      const float* crow = C + (size_t)(og * 64 + tid) * NC + n * TP;
      float p = 0.f, r = 0.f;
      f32x4 va = *(const f32x4*)(crow);
      f32x4 vb = *(const f32x4*)(crow + 4);
      for (int i = 0; i < TP; i += 8) {
        f32x4 na, nb;
        if (i + 8 < TP) {
          na = *(const f32x4*)(crow + i + 8);
          nb = *(const f32x4*)(crow + i + 12);
        }
        float u[8];
#pragma unroll
        for (int j = 0; j < 4; ++j) { u[j] = va[j]; u[4 + j] = vb[j]; }
#pragma unroll
        for (int j = 0; j < 8; ++j) {
          p = DSR * p + u[j];
          float v = p + r;
          bool s = (v >= THETA);
          r = DREF * (r - (s ? REFAMP : 0.f));
          spkb[(i + j) * 68 + tid] = s ? (unsigned char)1 : (unsigned char)0;
        }
        va = na; vb = nb;
      }
    }
    __syncthreads();
    if (tid < 128) {
#pragma unroll
      for (int k = 0; k < 4; ++k) {
        int t = tid + k * 128;
        float acc[O2];
#pragma unroll
        for (int o = 0; o < O2; ++o) acc[o] = 0.f;
        for (int row = 0; row < 64; ++row) {
          float s = (spkb[t * 68 + row] != 0) ? 1.f : 0.f;
#pragma unroll
          for (int o = 0; o < O2; ++o) acc[o] = fmaf(w2s[o * 64 + row], s, acc[o]);
        }
#pragma unroll
        for (int o = 0; o < O2; ++o)
          a2part[(((size_t)og * NB + n) * O2 + o) * TP + t] = acc[o];
      }
    }
  } else {
    float* atv = (float*)smem;    // [t][14]
    int blk = bx - 256;
    int n = blk >> 2, g = blk & 3;
    int o0 = g * 13;
    int cnt = (o0 + 13 <= OT) ? 13 : (OT - o0);   // 13,13,13,11
    int t0 = tid, t1 = tid + 256;
    {
      float acc0[13], acc1[13];
#pragma unroll
      for (int o = 0; o < 13; ++o) { acc0[o] = 0.f; acc1[o] = 0.f; }
      for (int f = 0; f < FT; ++f) {
        float x0 = (t0 < TT) ? xt[((size_t)n * FT + f) * TT + t0] : 0.f;
        float x1 = (t1 < TT) ? xt[((size_t)n * FT + f) * TT + t1] : 0.f;
#pragma unroll
        for (int o = 0; o < 13; ++o) {
          float w = (o < cnt) ? Wt[(o0 + o) * FT + f] : 0.f;
          acc0[o] = fmaf(w, x0, acc0[o]);
          acc1[o] = fmaf(w, x1, acc1[o]);
        }
      }
#pragma unroll
      for (int o = 0; o < 13; ++o) {
        atv[t0 * 14 + o] = acc0[o];
        atv[t1 * 14 + o] = acc1[o];
      }
    }
    __syncthreads();
    if (tid < cnt) {
      float p = 0.f, r = 0.f;
      unsigned char* op = s_tact + ((size_t)n * OT + o0 + tid) * TT;
      for (int i = 0; i < TT; i += 10) {
        float u[10];
#pragma unroll
        for (int j = 0; j < 10; ++j) u[j] = atv[(i + j) * 14 + tid];
#pragma unroll
        for (int j = 0; j < 10; ++j) {
          p = DSR * p + u[j];
          float v = p + r;
          bool s = (v >= THETA);
          r = DREF * (r - (s ? REFAMP : 0.f));
          op[i + j] = s ? (unsigned char)1 : (unsigned char)0;
        }
      }
    }
  }
}

// ============ K3b: og-reduce + vis psp scan -> u2s spike bytes ==============
__global__ void __launch_bounds__(256) k_vis(const float* __restrict__ a2part,
                                             unsigned char* __restrict__ u2s) {
  __shared__ float su[TP];
  int bx = blockIdx.x, tid = threadIdx.x;
  int n = bx / O2, o = bx - n * O2;
  float s0 = 0.f, s1 = 0.f;
#pragma unroll
  for (int og = 0; og < NB; ++og) {
    const float* row = a2part + (((size_t)og * NB + n) * O2 + o) * TP;
    s0 += row[tid];
    s1 += row[tid + 256];
  }
  su[tid] = s0;
  su[tid + 256] = s1;
  __syncthreads();
  if (tid == 0) {
    float p = 0.f, r = 0.f;
    unsigned char* op = u2s + ((size_t)n * O2 + o) * TP;
    for (int i = 0; i < TT; i += 10) {
      float u[10];
#pragma unroll
      for (int j = 0; j < 10; ++j) u[j] = su[i + j];
#pragma unroll
      for (int j = 0; j < 10; ++j) {
        p = DSR * p + u[j];
        float v = p + r;
        bool s = (v >= THETA);
        r = DREF * (r - (s ? REFAMP : 0.f));
        op[i + j] = s ? (unsigned char)1 : (unsigned char)0;
      }
    }
  }
}

// ============ K4: Wf @ [s_tact; s_vis] -> psp+spike -> out ==================
__global__ void __launch_bounds__(512) k_finish(const unsigned char* __restrict__ u2s,
                                                const unsigned char* __restrict__ s_tact,
                                                const float* __restrict__ Wf,
                                                float* __restrict__ out) {
  __shared__ float af[TP * 21];
  int n = blockIdx.x, t = threadIdx.x;
  if (t < TT) {
    float acc[OF];
#pragma unroll
    for (int o = 0; o < OF; ++o) acc[o] = 0.f;
    for (int f = 0; f < OT; ++f) {
      float s = (float)s_tact[((size_t)n * OT + f) * TT + t];
#pragma unroll
      for (int o = 0; o < OF; ++o) acc[o] = fmaf(Wf[o * 60 + f], s, acc[o]);
    }
#pragma unroll
    for (int f = 0; f < O2; ++f) {
      float s = (float)u2s[((size_t)n * O2 + f) * TP + t];
#pragma unroll
      for (int o = 0; o < OF; ++o) acc[o] = fmaf(Wf[o * 60 + OT + f], s, acc[o]);
    }
#pragma unroll
    for (int o = 0; o < OF; ++o) af[t * 21 + o] = acc[o];
  }
  __syncthreads();
  if (t < OF) {
    float p = 0.f, r = 0.f;
    float* op = out + ((size_t)n * OF + t) * TT;
    for (int i = 0; i < TT; i += 10) {
      float u[10];
#pragma unroll
      for (int j = 0; j < 10; ++j) u[j] = af[(i + j) * 21 + t];
#pragma unroll
      for (int j = 0; j < 10; ++j) {
        p = DSR * p + u[j];
        float v = p + r;
        bool s = (v >= THETA);
        r = DREF * (r - (s ? REFAMP : 0.f));
        op[i + j] = s ? 1.f : 0.f;
      }
    }
  }
}

extern "C" void kernel_launch(void* const* d_in, const int* in_sizes, int n_in,
                              void* d_out, int out_size, void* d_ws, size_t ws_size,
                              hipStream_t stream) {
  (void)in_sizes; (void)n_in; (void)out_size; (void)ws_size;
  const float* xt  = (const float*)d_in[0];
  const float* xv  = (const float*)d_in[1];
  const float* Wt  = (const float*)d_in[2];
  const float* Wv1 = (const float*)d_in[3];
  const float* Wv2 = (const float*)d_in[4];
  const float* Wf  = (const float*)d_in[5];
  float* out = (float*)d_out;

  char* ws = (char*)d_ws;
  size_t off = 0;
  auto carve = [&](size_t bytes) {
    char* p = ws + off;
    off += (bytes + 255) & ~(size_t)255;
    return p;
  };
  char*          H0    = carve((size_t)O1 * KP);
  char*          H1    = carve((size_t)O1 * KP);
  unsigned char* Bg    = (unsigned char*)carve((size_t)NKS * 8192 * 16);
  float*         a1    = (float*)carve((size_t)O1 * NC * 4);
  unsigned char* stact = (unsigned char*)carve((size_t)NB * OT * TT);
  float*         a2p   = (float*)carve((size_t)NB * NB * O2 * TP * 4);
  unsigned char* u2s   = (unsigned char*)carve((size_t)NB * O2 * TP);

  k_prep<<<dim3(1856), dim3(512), 0, stream>>>(xv, Wv1, Bg, H0, H1);
  k_gemm<<<dim3(512), dim3(512), 0, stream>>>(H0, H1, Bg, a1);
  k_spk1<<<dim3(320), dim3(256), 0, stream>>>(a1, Wv2, a2p, xt, Wt, stact);
  k_vis<<<dim3(160), dim3(256), 0, stream>>>(a2p, u2s);
  k_finish<<<dim3(NB), dim3(512), 0, stream>>>(u2s, stact, Wf, out);
}